// Round 8
// baseline (227.122 us; speedup 1.0000x reference)
//
#include <hip/hip_runtime.h>

// ---------- types ----------
typedef __attribute__((ext_vector_type(8))) short bfrag8;   // 8 bf16 bit patterns (4 VGPRs)
typedef __attribute__((ext_vector_type(4))) short bfrag4;
typedef __attribute__((ext_vector_type(4))) float f32x4;

#if defined(__has_builtin)
#if __has_builtin(__builtin_amdgcn_cvt_pk_bf16_f32)
#define HAVE_PK_BF16 1
#endif
#endif

// ---------- bf16 helpers ----------
__device__ __forceinline__ float bf2f(unsigned short h){
  unsigned u = ((unsigned)h) << 16;
  return __builtin_bit_cast(float, u);
}
__device__ __forceinline__ unsigned short f2bf(float f){
  unsigned u = __builtin_bit_cast(unsigned, f);
  u = u + 0x7FFFu + ((u >> 16) & 1u);        // round-to-nearest-even
  return (unsigned short)(u >> 16);
}
__device__ __forceinline__ unsigned pk2bf(float a, float b){
#ifdef HAVE_PK_BF16
  typedef __attribute__((ext_vector_type(2))) __bf16 bf16x2_t;
  bf16x2_t r = __builtin_amdgcn_cvt_pk_bf16_f32(a, b);
  return __builtin_bit_cast(unsigned, r);
#else
  return (unsigned)f2bf(a) | ((unsigned)f2bf(b) << 16);
#endif
}
__device__ __forceinline__ bfrag8 gload8(const unsigned short* p){
  int4 v = *(const int4*)p;
  return __builtin_bit_cast(bfrag8, v);
}
__device__ __forceinline__ bfrag8 lds_load8(const unsigned short* p){
  bfrag4 lo = *(const bfrag4*)p;
  bfrag4 hi = *(const bfrag4*)(p + 4);
  bfrag8 r;
#pragma unroll
  for (int j = 0; j < 4; j++){ r[j] = lo[j]; r[4+j] = hi[j]; }
  return r;
}
__device__ __forceinline__ f32x4 mfma16(bfrag8 a, bfrag8 b, f32x4 c){
  return __builtin_amdgcn_mfma_f32_16x16x32_bf16(a, b, c, 0, 0, 0);
}

// ---------- dtype-dispatched accessors (flag: 1 = tensor is f32) ----------
__device__ __forceinline__ float ldf(const void* p, size_t i, int f32){
  return f32 ? ((const float*)p)[i] : bf2f(((const unsigned short*)p)[i]);
}
__device__ __forceinline__ unsigned short ldbf(const void* p, size_t i, int f32){
  return f32 ? f2bf(((const float*)p)[i]) : ((const unsigned short*)p)[i];
}
__device__ __forceinline__ bfrag8 load8bf(const void* p, size_t base, int f32){
  if (f32){
    const float* f = (const float*)p + base;
    float4 x = *(const float4*)f;
    float4 y = *(const float4*)(f + 4);
    bfrag8 r;
    r[0]=(short)f2bf(x.x); r[1]=(short)f2bf(x.y); r[2]=(short)f2bf(x.z); r[3]=(short)f2bf(x.w);
    r[4]=(short)f2bf(y.x); r[5]=(short)f2bf(y.y); r[6]=(short)f2bf(y.z); r[7]=(short)f2bf(y.w);
    return r;
  }
  return gload8((const unsigned short*)p + base);
}

// ---------- reductions ----------
template<int CTRL>
__device__ __forceinline__ float dpp_add(float x){
  int xi = __builtin_bit_cast(int, x);
  int yi = __builtin_amdgcn_update_dpp(0, xi, CTRL, 0xF, 0xF, true);
  return x + __builtin_bit_cast(float, yi);
}
__device__ __forceinline__ float row16_sum(float x){
  x = dpp_add<0xB1>(x);    // quad_perm [1,0,3,2]
  x = dpp_add<0x4E>(x);    // quad_perm [2,3,0,1]
  x = dpp_add<0x141>(x);   // row_half_mirror
  x = dpp_add<0x140>(x);   // row_mirror
  return x;
}
__device__ __forceinline__ float xgrp_sum(float x){
  x += __shfl_xor(x, 16, 64);
  x += __shfl_xor(x, 32, 64);
  return x;
}
__device__ __forceinline__ int wave_isum(int x){
#pragma unroll
  for (int s = 1; s < 64; s <<= 1) x += __shfl_xor(x, s, 64);
  return x;
}

// k-slot -> logical-channel permutation for the bounced GEMMs (wg1/wg2/wo):
// bounce writes channel c at row-position pos(c)=4*(c&15)+(c>>4) (b64-contiguous
// per lane); reader consumes positions linearly, so B fragments use c(p).
__device__ __host__ __forceinline__ int permC(int p){ return (p >> 2) + 16 * (p & 3); }

// wfrag layout (ushort):
//   [0)       wq   identity-k   4096
//   [4096)    wk                4096
//   [8192)    wv                4096
//   [12288)   wg1  permuted-k   4096
//   [16384)   wg2  permuted-k   4096
//   [20480)   wo   permuted-k   4096
//   [24576)   ws1 frags (2 ks x 64 lane x 8 j, permuted)  1024
//   [25600)   wps frag  (64 lane x 8 j)                    512
#define WS1_OFF 24576
#define WPS_OFF 25600

// ============================================================================
// Kernel 0a: dtype sniffing — parallel, one wave per tensor.
// ============================================================================
struct Ptrs { const void* p[21]; int n[21]; };
struct PrepPtrs { const void* w[6]; const void* wp; const void* b[11]; };

__global__ void detect_kernel(Ptrs ptrs, int* flags){
  const int lane = threadIdx.x & 63;
  const int wid = blockIdx.x * 4 + (threadIdx.x >> 6);
  if (wid >= 21) return;
  if (wid == 2){ if (lane == 0) flags[2] = 0; return; }

  const unsigned short* p = (const unsigned short*)ptrs.p[wid];
  int m = ptrs.n[wid]; if (m > 128) m = 128;
  int insane = 0, evenZero = 0, evenCnt = 0, oddNZ = 0, oddCnt = 0;
#pragma unroll
  for (int s = 0; s < 2; s++){
    int i = lane + s*64;
    if (i < m){
      unsigned short h = p[i];
      int e = (h >> 7) & 0xFF;
      bool z = (h & 0x7FFF) == 0;
      if (!z && (e == 0xFF || e < 90 || e > 140)) insane++;
      if (i & 1){ oddCnt++;  if (!z) oddNZ++; }
      else      { evenCnt++; if (z)  evenZero++; }
    }
  }
  insane = wave_isum(insane);
  evenZero = wave_isum(evenZero); evenCnt = wave_isum(evenCnt);
  oddNZ = wave_isum(oddNZ);       oddCnt = wave_isum(oddCnt);
  if (lane == 0){
    int f = 0;
    if (insane > 0) f = 1;
    else if (evenZero * 4 >= evenCnt * 3 && oddNZ * 4 >= oddCnt * 3) f = 1;
    flags[wid] = f;
  }
}

// ============================================================================
// Kernel 0b: canonicalize params. Weights -> fragment-ordered bf16 (wg1/wg2/wo
// with permuted k); ws1 = wg1@1 and wps = wp@1 broadcast-column fragments for
// the MFMA LayerNorm-sum fold; biases/scales -> f32 (+ sum_bp, sum_bg1).
// ============================================================================
__global__ void prep_kernel(PrepPtrs pp, const int* __restrict__ flags,
                            unsigned short* __restrict__ wfrag,
                            unsigned short* __restrict__ wp_bf,
                            float* __restrict__ biases)
{
  const int tid = threadIdx.x;
  const int gid = blockIdx.x * 256 + tid;
  const int gstride = gridDim.x * 256;
  const int wflag[6] = {3,5,7,13,17,19};          // wq,wk,wv,wg1,wg2,wo
  for (int idx = gid; idx < 6*4096; idx += gstride){
    int m = idx >> 12;
    int r = idx & 4095;          // ((ks*4+t)*64 + lane)*8 + j
    int j = r & 7;
    int lane = (r >> 3) & 63;
    int kt = r >> 9;
    int ks = kt >> 2, t = kt & 3;
    int o = lane >> 4, rl = lane & 15;
    int kslot = ks*32 + o*8 + j;
    int k_log = (m >= 3) ? permC(kslot) : kslot;
    int src = k_log*64 + t*16 + rl;
    wfrag[idx] = ldbf(pp.w[m], src, flags[wflag[m]]);
  }
  if (blockIdx.x == 0){
    __shared__ float part[64][4];
    __shared__ float ws1sh[64];
    __shared__ float wpssh[3];
    // ws1[c] = sum_n wg1[c][n], 4-way split per channel
    {
      int c = tid >> 2, q = tid & 3;
      float s = 0.f;
#pragma unroll
      for (int u = 0; u < 16; u++) s += ldf(pp.w[3], c*64 + q*16 + u, flags[13]);
      part[c][q] = s;
    }
    __syncthreads();
    if (tid < 64) ws1sh[tid] = part[tid][0] + part[tid][1] + part[tid][2] + part[tid][3];
    __syncthreads();
    // wps[k] = sum_c wp[k][c]
    if (tid < 12){
      int k = tid >> 2, q = tid & 3;
      float s = 0.f;
#pragma unroll
      for (int u = 0; u < 16; u++) s += ldf(pp.wp, k*64 + q*16 + u, flags[9]);
      part[k][q] = s;
    }
    __syncthreads();
    if (tid < 3) wpssh[tid] = part[tid][0] + part[tid][1] + part[tid][2] + part[tid][3];
    if (tid == 4){
      float s = 0.f;
      for (int i = 0; i < 64; i++) s += ldf(pp.b[3], i, flags[10]);   // bp
      biases[704] = s;
    }
    if (tid == 5){
      float s = 0.f;
      for (int i = 0; i < 64; i++) s += ldf(pp.b[6], i, flags[14]);   // bg1
      biases[705] = s;
    }
    __syncthreads();
    for (int i = tid; i < 1024; i += 256){
      int j = i & 7, lane = (i >> 3) & 63, ks = i >> 9;
      int o = lane >> 4;
      int c = permC(ks*32 + o*8 + j);
      wfrag[WS1_OFF + i] = f2bf(ws1sh[c]);
    }
    for (int i = tid; i < 512; i += 256){
      int j = i & 7, lane = i >> 3;
      int o = lane >> 4;
      unsigned short v = 0;
      if (o == 0 && j < 3) v = f2bf(wpssh[j]);
      wfrag[WPS_OFF + i] = v;
    }
    for (int i = tid; i < 192; i += 256) wp_bf[i] = ldbf(pp.wp, i, flags[9]);
    const int bflag[11] = {4,6,8,10,11,12,14,15,16,18,20};
    for (int i = tid; i < 11*64; i += 256){
      int m = i >> 6;
      biases[i] = ldf(pp.b[m], i & 63, flags[bflag[m]]);
    }
  }
}

// ============================================================================
// Kernel 1: q,k,v = features @ {wq,wk,wv} + bias -> bf16 scratch in SWIZZLED
// layout: (row, c) at row*64 + 4*(c&15) + (c>>4)  (lane's 4 channels = 8B).
// ============================================================================
__global__ __launch_bounds__(256, 2)
void qkv_kernel(const void* __restrict__ feat,
                const unsigned short* __restrict__ wfrag,
                const float* __restrict__ biases,
                unsigned short* __restrict__ q_ws, unsigned short* __restrict__ k_ws,
                unsigned short* __restrict__ v_ws, const int* __restrict__ flags, int N)
{
  const int F_feat = flags[1];
  const int lane = threadIdx.x & 63;
  const int wave = threadIdx.x >> 6;
  const int o = lane >> 4, rl = lane & 15;

  bfrag8 wqf[2][4], wkf[2][4], wvf[2][4];
#pragma unroll
  for (int ks = 0; ks < 2; ks++)
#pragma unroll
    for (int t = 0; t < 4; t++){
      int off = ((ks*4 + t)*64 + lane)*8;
      wqf[ks][t] = gload8(wfrag + off);
      wkf[ks][t] = gload8(wfrag + 4096 + off);
      wvf[ks][t] = gload8(wfrag + 8192 + off);
    }
  float bqC[4], bkC[4], bvC[4];
#pragma unroll
  for (int t = 0; t < 4; t++){
    bqC[t] = biases[0*64 + t*16 + rl];
    bkC[t] = biases[1*64 + t*16 + rl];
    bvC[t] = biases[2*64 + t*16 + rl];
  }

  const int ntiles = (N + 15) >> 4;
  for (int tile = blockIdx.x*4 + wave; tile < ntiles; tile += gridDim.x*4){
    const int n0 = tile * 16;
    int ar = n0 + rl; if (ar >= N) ar = N - 1;
    bfrag8 a[2];
#pragma unroll
    for (int ks = 0; ks < 2; ks++) a[ks] = load8bf(feat, (size_t)ar*64 + ks*32 + o*8, F_feat);

    f32x4 zq[4], zk[4], zv[4];
#pragma unroll
    for (int t = 0; t < 4; t++){
      f32x4 aq = {0.f,0.f,0.f,0.f}, ak = {0.f,0.f,0.f,0.f}, av = {0.f,0.f,0.f,0.f};
#pragma unroll
      for (int ks = 0; ks < 2; ks++){
        aq = mfma16(a[ks], wqf[ks][t], aq);
        ak = mfma16(a[ks], wkf[ks][t], ak);
        av = mfma16(a[ks], wvf[ks][t], av);
      }
      zq[t] = aq; zk[t] = ak; zv[t] = av;
    }
#pragma unroll
    for (int q = 0; q < 4; q++){
      size_t row = n0 + o*4 + q;
      if ((int)row < N){
        size_t e = row*64 + 4*rl;
        uint2 u;
        u.x = pk2bf(zq[0][q]+bqC[0], zq[1][q]+bqC[1]);
        u.y = pk2bf(zq[2][q]+bqC[2], zq[3][q]+bqC[3]);
        *(uint2*)(q_ws + e) = u;
        u.x = pk2bf(zk[0][q]+bkC[0], zk[1][q]+bkC[1]);
        u.y = pk2bf(zk[2][q]+bkC[2], zk[3][q]+bkC[3]);
        *(uint2*)(k_ws + e) = u;
        u.x = pk2bf(zv[0][q]+bvC[0], zv[1][q]+bvC[1]);
        u.y = pk2bf(zv[2][q]+bvC[2], zv[3][q]+bvC[3]);
        *(uint2*)(v_ws + e) = u;
      }
    }
  }
}

// ============================================================================
// Kernel 2: fused point-transformer. LN sums folded into MFMA (ws1/wps
// broadcast columns); bounce via b64 writes with k-permuted weights.
// NOTE: weight fragments live in VGPRs — do NOT tighten launch bounds
// (round-4's (64,4) clamped VGPR to 64 and spilled ~1 GB/launch).
// ============================================================================
__global__ __launch_bounds__(256, 2)
void pt_kernel(const void* __restrict__ points,
               const void* __restrict__ feat,
               const int* __restrict__ nidx,
               const unsigned short* __restrict__ q_ws,
               const unsigned short* __restrict__ k_ws,
               const unsigned short* __restrict__ v_ws,
               const unsigned short* __restrict__ wfrag,
               const unsigned short* __restrict__ wp_bf,
               const float* __restrict__ biases,
               const int* __restrict__ flags, void* __restrict__ out, int N)
{
  __shared__ unsigned short xbuf[4][16][68];   // per-wave bounce, pos(c)=4*(c&15)+(c>>4)
  __shared__ unsigned short ybuf[4][64];

  const int F_pts = flags[0], F_feat = flags[1];
  const int lane = threadIdx.x & 63;
  const int wave = threadIdx.x >> 6;
  const int o = lane >> 4, rl = lane & 15;

  bfrag8 wg1f[2][4], wg2f[2][4], wof[2][4], ws1f[2], wpsf;
#pragma unroll
  for (int ks = 0; ks < 2; ks++)
#pragma unroll
    for (int t = 0; t < 4; t++){
      int off = ((ks*4 + t)*64 + lane)*8;
      wg1f[ks][t] = gload8(wfrag + 12288 + off);
      wg2f[ks][t] = gload8(wfrag + 16384 + off);
      wof[ks][t]  = gload8(wfrag + 20480 + off);
    }
#pragma unroll
  for (int ks = 0; ks < 2; ks++) ws1f[ks] = gload8(wfrag + WS1_OFF + (ks*64 + lane)*8);
  wpsf = gload8(wfrag + WPS_OFF + lane*8);

  bfrag8 wpf[4];
#pragma unroll
  for (int t = 0; t < 4; t++){
    bfrag8 a = {0,0,0,0,0,0,0,0};
    if (o == 0){
#pragma unroll
      for (int j = 0; j < 3; j++) a[j] = (short)wp_bf[j*64 + t*16 + rl];
    }
    wpf[t] = a;
  }
  float bpC[4], gpC[4], bePC[4], bg1C[4], ggC[4], beGC[4], bg2C[4], boC[4];
#pragma unroll
  for (int t = 0; t < 4; t++){
    int c = t*16 + rl;
    bpC[t]  = biases[3*64 + c];  gpC[t]  = biases[4*64 + c];  bePC[t] = biases[5*64 + c];
    bg1C[t] = biases[6*64 + c];  ggC[t]  = biases[7*64 + c];  beGC[t] = biases[8*64 + c];
    bg2C[t] = biases[9*64 + c];  boC[t]  = biases[10*64 + c];
  }
  const float sum_bp  = biases[704];
  const float sum_bg1 = biases[705];

  const int wstride = gridDim.x * 4;
  for (int n = blockIdx.x*4 + wave; n < N; n += wstride){
    int4 jqv = *(const int4*)(nidx + n*16 + o*4);      // C-layout rows
    const int jr = nidx[n*16 + rl];                    // A-layout row (p path)
    int jq[4] = {jqv.x, jqv.y, jqv.z, jqv.w};

    ushort4 uq = *(const ushort4*)(q_ws + (size_t)n*64 + 4*rl);
    ushort4 gk_pk[4], gv_pk[4];
#pragma unroll
    for (int q = 0; q < 4; q++){
      size_t e = (size_t)jq[q]*64 + 4*rl;
      gk_pk[q] = *(const ushort4*)(k_ws + e);
      gv_pk[q] = *(const ushort4*)(v_ws + e);
    }
    const float res = ldf(feat, (size_t)n*64 + lane, F_feat);
    float rel[3];
#pragma unroll
    for (int d = 0; d < 3; d++)
      rel[d] = ldf(points, (size_t)jr*3 + d, F_pts) - ldf(points, (size_t)n*3 + d, F_pts);

    // ---- p = relu(LN(rel @ wp + bp)); s folded via wps MFMA ----
    bfrag8 ap = {0,0,0,0,0,0,0,0};
    if (o == 0){
#pragma unroll
      for (int d = 0; d < 3; d++) ap[d] = (short)f2bf(rel[d]);
    }
    f32x4 pacc[4];
#pragma unroll
    for (int t = 0; t < 4; t++){
      f32x4 z = {0.f,0.f,0.f,0.f};
      pacc[t] = mfma16(ap, wpf[t], z);
    }
    f32x4 zz = {0.f,0.f,0.f,0.f};
    f32x4 pacc_s = mfma16(ap, wpsf, zz);

    float p_val[4][4];                        // [t][q], C-layout
#pragma unroll
    for (int q = 0; q < 4; q++){
      float xv[4]; float s2 = 0.f;
#pragma unroll
      for (int t = 0; t < 4; t++){ xv[t] = pacc[t][q] + bpC[t]; s2 += xv[t]*xv[t]; }
      s2 = row16_sum(s2);
      float mu = (pacc_s[q] + sum_bp) * (1.f/64.f);
      float var = s2 * (1.f/64.f) - mu*mu;
      float rs = rsqrtf(var + 1e-5f);
#pragma unroll
      for (int t = 0; t < 4; t++){
        float a = rs * gpC[t];
        p_val[t][q] = fmaxf(xv[t]*a + (bePC[t] - mu*a), 0.f);
      }
    }

    // ---- attn_in = q - gk + p -> b64 bounce ----
    float qC[4];
    qC[0] = bf2f(uq.x); qC[1] = bf2f(uq.y); qC[2] = bf2f(uq.z); qC[3] = bf2f(uq.w);
#pragma unroll
    for (int q = 0; q < 4; q++){
      float a0 = qC[0] - bf2f(gk_pk[q].x) + p_val[0][q];
      float a1 = qC[1] - bf2f(gk_pk[q].y) + p_val[1][q];
      float a2 = qC[2] - bf2f(gk_pk[q].z) + p_val[2][q];
      float a3 = qC[3] - bf2f(gk_pk[q].w) + p_val[3][q];
      uint2 w2; w2.x = pk2bf(a0, a1); w2.y = pk2bf(a2, a3);
      *(uint2*)&xbuf[wave][o*4 + q][4*rl] = w2;
    }
    bfrag8 af0 = lds_load8(&xbuf[wave][rl][o*8]);
    bfrag8 af1 = lds_load8(&xbuf[wave][rl][32 + o*8]);

    // ---- GEMM1 (k-permuted wg1) + s-fold ----
    f32x4 hacc[4] = {{0.f,0.f,0.f,0.f},{0.f,0.f,0.f,0.f},{0.f,0.f,0.f,0.f},{0.f,0.f,0.f,0.f}};
#pragma unroll
    for (int t = 0; t < 4; t++){
      hacc[t] = mfma16(af0, wg1f[0][t], hacc[t]);
      hacc[t] = mfma16(af1, wg1f[1][t], hacc[t]);
    }
    f32x4 sacc = {0.f,0.f,0.f,0.f};
    sacc = mfma16(af0, ws1f[0], sacc);
    sacc = mfma16(af1, ws1f[1], sacc);

    // ---- LN2 + relu -> h; b64 bounce ----
#pragma unroll
    for (int q = 0; q < 4; q++){
      float xv[4]; float s2 = 0.f;
#pragma unroll
      for (int t = 0; t < 4; t++){ xv[t] = hacc[t][q] + bg1C[t]; s2 += xv[t]*xv[t]; }
      s2 = row16_sum(s2);
      float mu = (sacc[q] + sum_bg1) * (1.f/64.f);
      float var = s2 * (1.f/64.f) - mu*mu;
      float rs = rsqrtf(var + 1e-5f);
      float h0, h1, h2, h3;
      {
        float a0 = rs * ggC[0]; h0 = fmaxf(xv[0]*a0 + (beGC[0] - mu*a0), 0.f);
        float a1 = rs * ggC[1]; h1 = fmaxf(xv[1]*a1 + (beGC[1] - mu*a1), 0.f);
        float a2 = rs * ggC[2]; h2 = fmaxf(xv[2]*a2 + (beGC[2] - mu*a2), 0.f);
        float a3 = rs * ggC[3]; h3 = fmaxf(xv[3]*a3 + (beGC[3] - mu*a3), 0.f);
      }
      uint2 w2; w2.x = pk2bf(h0, h1); w2.y = pk2bf(h2, h3);
      *(uint2*)&xbuf[wave][o*4 + q][4*rl] = w2;
    }
    bfrag8 hf0 = lds_load8(&xbuf[wave][rl][o*8]);
    bfrag8 hf1 = lds_load8(&xbuf[wave][rl][32 + o*8]);
    f32x4 wacc[4] = {{0.f,0.f,0.f,0.f},{0.f,0.f,0.f,0.f},{0.f,0.f,0.f,0.f},{0.f,0.f,0.f,0.f}};
#pragma unroll
    for (int t = 0; t < 4; t++){
      wacc[t] = mfma16(hf0, wg2f[0][t], wacc[t]);
      wacc[t] = mfma16(hf1, wg2f[1][t], wacc[t]);
    }

    // ---- softmax over neighbors (no max-shift: |w| << 88) ----
    float y[4];
#pragma unroll
    for (int t = 0; t < 4; t++){
      float se = 0.f, z = 0.f;
#pragma unroll
      for (int q = 0; q < 4; q++){
        float e = __expf(wacc[t][q] + bg2C[t]);
        float gv = (t==0) ? bf2f(gv_pk[q].x) : (t==1) ? bf2f(gv_pk[q].y)
                 : (t==2) ? bf2f(gv_pk[q].z) : bf2f(gv_pk[q].w);
        se += e;
        z  += e * (gv + p_val[t][q]);
      }
      se = xgrp_sum(se); z = xgrp_sum(z);
      y[t] = z * __builtin_amdgcn_rcpf(se);
    }

    // ---- out = y @ wo + bo + residual (k-permuted wo, b64 ybuf) ----
    if (o == 0){
      uint2 w2; w2.x = pk2bf(y[0], y[1]); w2.y = pk2bf(y[2], y[3]);
      *(uint2*)&ybuf[wave][4*rl] = w2;
    }
    bfrag8 yf0 = lds_load8(&ybuf[wave][o*8]);
    bfrag8 yf1 = lds_load8(&ybuf[wave][32 + o*8]);
    f32x4 oacc[4] = {{0.f,0.f,0.f,0.f},{0.f,0.f,0.f,0.f},{0.f,0.f,0.f,0.f},{0.f,0.f,0.f,0.f}};
#pragma unroll
    for (int t = 0; t < 4; t++){
      oacc[t] = mfma16(yf0, wof[0][t], oacc[t]);
      oacc[t] = mfma16(yf1, wof[1][t], oacc[t]);
    }

    float ov = 0.f;
#pragma unroll
    for (int t = 0; t < 4; t++) if (o == t) ov = oacc[t][0] + boC[t];
    float outv = ov + res;
    if (F_feat) ((float*)out)[(size_t)n*64 + lane] = outv;
    else ((unsigned short*)out)[(size_t)n*64 + lane] = f2bf(outv);
  }
}

// ============================================================================
extern "C" void kernel_launch(void* const* d_in, const int* in_sizes, int n_in,
                              void* d_out, int out_size, void* d_ws, size_t ws_size,
                              hipStream_t stream)
{
  const int N = in_sizes[1] / 64;

  unsigned short* q_ws = (unsigned short*)d_ws;
  unsigned short* k_ws = q_ws + (size_t)N * 64;
  unsigned short* v_ws = k_ws + (size_t)N * 64;
  char* base = (char*)d_ws + (size_t)3 * N * 64 * sizeof(unsigned short);
  int*            flags  = (int*)base;                            // 128 B
  unsigned short* wfrag  = (unsigned short*)(base + 256);         // 26112*2 = 52224 B
  unsigned short* wp_bf  = (unsigned short*)(base + 256 + 53248); // 384 B (pad 512)
  float*          biases = (float*)(base + 256 + 53248 + 512);    // 706*4 B

  Ptrs ptrs;
  for (int i = 0; i < 21; i++){ ptrs.p[i] = d_in[i]; ptrs.n[i] = in_sizes[i]; }
  PrepPtrs pp;
  pp.w[0] = d_in[3];  pp.w[1] = d_in[5];  pp.w[2] = d_in[7];
  pp.w[3] = d_in[13]; pp.w[4] = d_in[17]; pp.w[5] = d_in[19];
  pp.wp = d_in[9];
  pp.b[0] = d_in[4];  pp.b[1] = d_in[6];  pp.b[2] = d_in[8];  pp.b[3] = d_in[10];
  pp.b[4] = d_in[11]; pp.b[5] = d_in[12]; pp.b[6] = d_in[14]; pp.b[7] = d_in[15];
  pp.b[8] = d_in[16]; pp.b[9] = d_in[18]; pp.b[10] = d_in[20];

  detect_kernel<<<6, 256, 0, stream>>>(ptrs, flags);
  prep_kernel<<<32, 256, 0, stream>>>(pp, flags, wfrag, wp_bf, biases);
  qkv_kernel<<<512, 256, 0, stream>>>(d_in[1], wfrag, biases, q_ws, k_ws, v_ws, flags, N);
  pt_kernel<<<1024, 256, 0, stream>>>(d_in[0], d_in[1], (const int*)d_in[2], q_ws, k_ws, v_ws,
                                      wfrag, wp_bf, biases, flags, d_out, N);
}